// Round 11
// baseline (150.197 us; speedup 1.0000x reference)
//
#include <hip/hip_runtime.h>
#include <hip/hip_fp16.h>
#include <math.h>

// CTC forward loss (warp-ctc semantics). T=1024, B=64, V=128, L=256, S=513.
//
// Round 12: break the dependency chains.
//  Evidence R4/R7/R8/R9/R10: ~65 cyc/step stall invariant under 4 memory
//  schemes and instruction cuts -> the stall is VALU dep-latency exposure
//  at 1 wave/SIMD (3-deep chain add->fma->mul per cell per step).
//  - Step refactored so every cell self-recurrence is ONE pk_fma:
//      P' = P*E + Z   with Z computed off-chain from old values.
//    Same op count (10 pk ops), 3x shorter serial chains.
//  - Blanks moved to SGPR pairs (VOP3P allows one 64-bit scalar src):
//    drops the ebk VGPR prefetch and 1 VMEM/step; blank SGPRs prefetched
//    one 16-step block ahead (uniform loads -> s_load through K$).
//  - Probs: one block per (b, 32 rows), 8 rows/wave -> labels loaded once
//    per wave (label traffic 67MB -> 8MB), 8 independent softmaxes give
//    ILP over the serial DPP-reduce chains. Block x=32 is pure pad.

#define L2E 1.4426950408889634f
#define LN2 0.6931471805599453f

constexpr int T   = 1024;
constexpr int B   = 64;
constexpr int V   = 128;
constexpr int L   = 256;
constexpr int RW  = 256;        // ushorts per P row: 256 label probs = 512 B
constexpr int TP  = T + 32;     // padded time rows per batch

typedef float v2f __attribute__((ext_vector_type(2)));
typedef unsigned int v2u __attribute__((ext_vector_type(2)));

// ---- VOP3P packed-fp32 helpers (gfx90a+; full-rate dual fp32) ----
__device__ __forceinline__ v2f pk_fma(v2f a, v2f b, v2f c) {
  v2f d; asm("v_pk_fma_f32 %0, %1, %2, %3" : "=v"(d) : "v"(a), "v"(b), "v"(c));
  return d;
}
__device__ __forceinline__ v2f pk_mul(v2f a, v2f b) {
  v2f d; asm("v_pk_mul_f32 %0, %1, %2" : "=v"(d) : "v"(a), "v"(b)); return d;
}
// variants with the second operand as a wave-uniform SGPR pair
__device__ __forceinline__ v2f pk_mul_s(v2f a, v2f sb) {
  v2f d; asm("v_pk_mul_f32 %0, %1, %2" : "=v"(d) : "v"(a), "s"(sb)); return d;
}
__device__ __forceinline__ v2f pk_fma_s(v2f a, v2f sb, v2f c) {
  v2f d; asm("v_pk_fma_f32 %0, %1, %2, %3" : "=v"(d) : "v"(a), "s"(sb), "v"(c));
  return d;
}

// ---- DPP helpers (gfx9 ctrl codes: 0x111+ row_shr, 0x138 wave_shr:1,
//      0x142 row_bcast15, 0x143 row_bcast31) ----
template <int CTRL>
__device__ __forceinline__ float fdpp0(float x) {        // invalid lanes -> 0
  return __int_as_float(__builtin_amdgcn_update_dpp(
      0, __float_as_int(x), CTRL, 0xf, 0xf, true));
}
template <int CTRL>
__device__ __forceinline__ float fdppk(float x) {        // invalid lanes -> keep
  return __int_as_float(__builtin_amdgcn_update_dpp(
      __float_as_int(x), __float_as_int(x), CTRL, 0xf, 0xf, false));
}

__device__ __forceinline__ float wave_bcast63(float x) {
  return __int_as_float(__builtin_amdgcn_readlane(__float_as_int(x), 63));
}

__device__ __forceinline__ float wave_max(float x) {     // any sign
  x = fmaxf(x, fdppk<0x111>(x));
  x = fmaxf(x, fdppk<0x112>(x));
  x = fmaxf(x, fdppk<0x114>(x));
  x = fmaxf(x, fdppk<0x118>(x));
  x = fmaxf(x, fdppk<0x142>(x));
  x = fmaxf(x, fdppk<0x143>(x));
  return wave_bcast63(x);
}
__device__ __forceinline__ float wave_sum_nn(float x) {  // x >= 0
  x += fdpp0<0x111>(x);
  x += fdpp0<0x112>(x);
  x += fdpp0<0x114>(x);
  x += fdpp0<0x118>(x);
  x += fdpp0<0x142>(x);
  x += fdpp0<0x143>(x);
  return wave_bcast63(x);
}

__device__ __forceinline__ float h2f(uint bits) {
  return __half2float(__ushort_as_half((ushort)bits));
}

// ---------------- prologue: emission probabilities ----------------
// One block per (b, 32-row chunk); 4 waves x 8 rows. Labels loaded once per
// wave and reused for 8 rows. Per row: in-register softmax, ds_bpermute
// gathers, paired output u.x=(e0|e2<<16), u.y=(e1|e3<<16); blank stored as
// a duplicated fp32 pair. Block x==32 (rows 1024..1055) is pure zero pad.
__global__ __launch_bounds__(256) void ctc_probs_kernel(
    const float* __restrict__ acts,        // (T, B, V)
    const int* __restrict__ labels,        // (B, L)
    ushort* __restrict__ P,                // (B, TP, RW) fp16 bits, 512B rows
    float* __restrict__ Pbk) {             // (B, TP) duplicated fp32 pairs
  const int w    = threadIdx.x >> 6;
  const int lane = threadIdx.x & 63;
  const int b    = blockIdx.y;
  const int tb   = blockIdx.x * 32 + w * 8;   // first of this wave's 8 rows

  if (tb >= T) {                            // pad rows: zeros
    #pragma unroll
    for (int r = 0; r < 8; ++r) {
      uint2 z; z.x = 0u; z.y = 0u;
      *(uint2*)(P + ((size_t)b * TP + tb + r) * RW + 4 * lane) = z;
    }
    if (lane < 8) {
      v2f zp; zp.x = 0.f; zp.y = 0.f;
      *(v2f*)(Pbk + ((size_t)b * TP + tb + lane) * 2) = zp;
    }
    return;
  }

  // labels once per wave; bpermute addresses/shifts precomputed
  const int4 lvv = *(const int4*)(labels + (size_t)b * L + 4 * lane);
  const int ba0 = (lvv.x & ~1) * 2, sh0 = (lvv.x & 1) << 4;
  const int ba1 = (lvv.y & ~1) * 2, sh1 = (lvv.y & 1) << 4;
  const int ba2 = (lvv.z & ~1) * 2, sh2 = (lvv.z & 1) << 4;
  const int ba3 = (lvv.w & ~1) * 2, sh3 = (lvv.w & 1) << 4;

  #pragma unroll
  for (int r = 0; r < 8; ++r) {
    const int t = tb + r;
    const float* row = acts + ((size_t)t * B + b) * V;
    const float2 v2 = *(const float2*)(row + 2 * lane);
    const float e0 = exp2f(fmaf(v2.x, L2E, -32.0f));
    const float e1 = exp2f(fmaf(v2.y, L2E, -32.0f));
    const float sm = wave_sum_nn(e0 + e1);
    const float rc = __builtin_amdgcn_rcpf(sm);
    const auto pk = __builtin_amdgcn_cvt_pkrtz(e0 * rc, e1 * rc);
    uint hp;                                // [p_{2l} | p_{2l+1} << 16]
    __builtin_memcpy(&hp, &pk, 4);
    const uint g0 = (uint)__builtin_amdgcn_ds_bpermute(ba0, (int)hp);
    const uint g1 = (uint)__builtin_amdgcn_ds_bpermute(ba1, (int)hp);
    const uint g2 = (uint)__builtin_amdgcn_ds_bpermute(ba2, (int)hp);
    const uint g3 = (uint)__builtin_amdgcn_ds_bpermute(ba3, (int)hp);
    const uint h0 = (g0 >> sh0) & 0xffffu;
    const uint h1 = (g1 >> sh1) & 0xffffu;
    const uint h2 = (g2 >> sh2);
    const uint h3 = (g3 >> sh3);
    uint2 o;
    o.x = h0 | (h2 << 16);                  // pair (e0, e2)
    o.y = h1 | (h3 << 16);                  // pair (e1, e3)
    *(uint2*)(P + ((size_t)b * TP + t) * RW + 4 * lane) = o;
    if (lane == 0) {
      const float pb = e0 * rc;             // vocab 0 = lane0's p0
      v2f bp; bp.x = pb; bp.y = pb;
      *(v2f*)(Pbk + ((size_t)b * TP + t) * 2) = bp;
    }
  }
}

// ---------------- DP kernel: one wave per batch ----------------
// Lane l owns cells 8l..8l+7 as pairs P0=(c0,c4) P1=(c1,c5) P2=(c2,c6)
// P3=(c3,c7); lane 63 additionally owns cell 512 in a8.
__global__ __launch_bounds__(64) void ctc_dp_kernel(
    const ushort* __restrict__ P,
    const float* __restrict__ Pbk,
    const int* __restrict__ labels,
    const int* __restrict__ act_lens,
    const int* __restrict__ label_lens,
    float* __restrict__ out) {
  const int b    = blockIdx.x;
  const int lane = threadIdx.x;
  const ushort* __restrict__ Pb = P + (size_t)b * TP * RW;
  const float*  __restrict__ Bk = Pbk + (size_t)b * TP * 2;

  // skip-transition flags for the 4 odd cells (labels 4l..4l+3)
  const int4 lv   = *(const int4*)(labels + (size_t)b * L + 4 * lane);
  const int prevw = __builtin_amdgcn_update_dpp(0, lv.w, 0x138, 0xf, 0xf, true);
  const float f0 = (lane > 0 && lv.x != 0 && lv.x != prevw) ? 1.f : 0.f;
  const float f1 = (lv.y != 0 && lv.y != lv.x) ? 1.f : 0.f;
  const float f2 = (lv.z != 0 && lv.z != lv.y) ? 1.f : 0.f;
  const float f3 = (lv.w != 0 && lv.w != lv.z) ? 1.f : 0.f;
  v2f F02; F02.x = f0; F02.y = f2;          // skips into P1 = (c1, c5)
  v2f F13; F13.x = f1; F13.y = f3;          // skips into P3 = (c3, c7)

  const int AL = act_lens[b];

  // ---- t=0 init (linear domain; unreachable cells = 0) ----
  v2f P0, P1, P2, P3;
  P0.x=0.f; P0.y=0.f; P1.x=0.f; P1.y=0.f;
  P2.x=0.f; P2.y=0.f; P3.x=0.f; P3.y=0.f;
  float a8 = 0.f;
  {
    const uint2 u0 = *(const uint2*)(Pb + 4 * lane);
    const v2f bk0  = *(const v2f*)(Bk);
    const float eb0 = bk0.x;                // blank prob at t=0
    const float e00 = h2f(u0.x);            // label-0 prob at t=0 (pair lo)
    if (lane == 0) { P0.x = eb0; P1.x = e00; }
  }
  int iacc = 0;        // accumulated log2 of renorm scales (wave-uniform)
  float pend = 1.0f;   // wave-maxed state max, measured 2 steps before apply

  // Distributed step: every cell self-recurrence is ONE pk_fma; the other
  // term is computed off-chain from old values. eb is an SGPR pair.
  auto step = [&](v2u u, v2f eb) {
    const float pc = fdpp0<0x138>(P3.y);    // prev lane's c7 (lane0 -> 0)
    v2f Q; Q.x = pc; Q.y = P3.x;            // (c_{-1}, c3_old)
    v2f E02, E13;
    E02.x = h2f(u.x); E02.y = h2f(u.x >> 16);
    E13.x = h2f(u.y); E13.y = h2f(u.y >> 16);
    const v2f A1 = pk_fma(F02, Q, P0);      // (c0+f0*pc,    c4+f2*c3)
    const v2f A3 = pk_fma(F13, P1, P2);     // (c2+f1*c1,    c6+f3*c5)
    const v2f ZQ = pk_mul_s(Q, eb);         // (pc*eb,       c3*eb)
    const v2f Z2 = pk_mul_s(P1, eb);        // (c1*eb,       c5*eb)
    const v2f Z1 = pk_mul(A1, E02);
    const v2f Z3 = pk_mul(A3, E13);
    const float z8 = P3.y * eb.x;           // c7*eb (valid on lane 63)
    P0 = pk_fma_s(P0, eb, ZQ);              // c0*eb + pc*eb, c4*eb + c3*eb
    P1 = pk_fma(P1, E02, Z1);
    P2 = pk_fma_s(P2, eb, Z2);
    P3 = pk_fma(P3, E13, Z3);
    a8 = fmaf(a8, eb.x, z8);                // (a8 + c7)*eb
  };

  auto measure = [&]() {                    // start wave-max; used 2 steps on
    float m = fmaxf(fmaxf(fmaxf(P0.x, P0.y), fmaxf(P1.x, P1.y)),
                    fmaxf(fmaxf(P2.x, P2.y), fmaxf(P3.x, P3.y)));
    m = fmaxf(m, a8);
    pend = wave_max(m);
  };
  auto apply = [&]() {                      // pow-2 scale 2^(175-e), exact.
    // +48 headroom: post-apply max ~2^48*d^2; 16-step dip stays normal for
    // per-step max-decay d >= 2^-9.7 (typical d ~ 2^-4).
    const uint mb = __float_as_uint(pend);
    int e = (int)((mb >> 23) & 0xffu); if (e < 48) e = 48;
    const float r = __uint_as_float((uint)(302 - e) << 23);
    iacc += (e - 175);
    v2f rr; rr.x = r; rr.y = r;
    P0 = pk_mul(P0, rr); P1 = pk_mul(P1, rr);
    P2 = pk_mul(P2, rr); P3 = pk_mul(P3, rr);
    a8 *= r;
  };

  // ---- prefetch: P rows 16 deep (VGPR), blanks 1 block ahead (SGPR) ----
  uint2 evi[16];
  #pragma unroll
  for (int k = 0; k < 16; ++k)
    evi[k] = *(const uint2*)(Pb + (size_t)(1 + k) * RW + 4 * lane);
  v2f ebq[16];                              // blanks for current block
  #pragma unroll
  for (int k = 0; k < 16; ++k)
    ebq[k] = *(const v2f*)(Bk + (size_t)(1 + k) * 2);

  const ushort* pf = Pb + (size_t)17 * RW;  // row t+16 for t=1
  int t0 = 1;
  #pragma unroll 1
  for (int blk = 0; blk < 64; ++blk) {      // 64 x 16 = steps t=1..1024
    v2f ebn[16];                            // next block blanks (pad-safe)
    {
      const float* bn = Bk + (size_t)(t0 + 16) * 2;   // rows <= 1040 < TP
      #pragma unroll
      for (int k = 0; k < 16; ++k) ebn[k] = *(const v2f*)(bn + 2 * k);
    }
    const ushort* pfA = pf;                 // dual bases: offsets fit 13-bit
    const ushort* pfB = pf + (size_t)8 * RW;
    const bool fast = (t0 + 16 <= AL);
    if (fast) {
      #pragma unroll
      for (int k = 0; k < 16; ++k) {
        const uint2 uu = evi[k];
        v2u u; u.x = uu.x; u.y = uu.y;
        evi[k] = *(const uint2*)(((k < 8) ? pfA : pfB)
                                 + (size_t)(k & 7) * RW + 4 * lane);
        step(u, ebq[k]);
        if (k == 13) measure();
        if (k == 15) apply();
      }
    } else {
      #pragma unroll
      for (int k = 0; k < 16; ++k) {
        const uint2 uu = evi[k];
        v2u u; u.x = uu.x; u.y = uu.y;
        evi[k] = *(const uint2*)(((k < 8) ? pfA : pfB)
                                 + (size_t)(k & 7) * RW + 4 * lane);
        if ((t0 + k) < AL) step(u, ebq[k]); // AL wave-uniform: scalar branch
        if (k == 13) measure();
        if (k == 15) apply();
      }
    }
    #pragma unroll
    for (int k = 0; k < 16; ++k) ebq[k] = ebn[k];
    t0 += 16;
    pf += (size_t)16 * RW;
  }

  // ---- epilogue: -ln( (a[end] + a[end-1]) * 2^iacc ) ----
  // cell map: base+0=P0.x +1=P1.x +2=P2.x +3=P3.x +4=P0.y +5=P1.y +6=P2.y +7=P3.y
  const int end  = 2 * label_lens[b];
  const int base = 8 * lane;
  float sel = 0.f;
  if (base     == end || base     == end - 1) sel += P0.x;
  if (base + 1 == end || base + 1 == end - 1) sel += P1.x;
  if (base + 2 == end || base + 2 == end - 1) sel += P2.x;
  if (base + 3 == end || base + 3 == end - 1) sel += P3.x;
  if (base + 4 == end || base + 4 == end - 1) sel += P0.y;
  if (base + 5 == end || base + 5 == end - 1) sel += P1.y;
  if (base + 6 == end || base + 6 == end - 1) sel += P2.y;
  if (base + 7 == end || base + 7 == end - 1) sel += P3.y;
  if (lane == 63 && (end == 512 || end - 1 == 512)) sel += a8;
  sel = wave_sum_nn(sel);
  if (lane == 0) {
    const float cost = -((log2f(sel) + (float)iacc) * LN2);
    atomicAdd(out, cost);
  }
}

extern "C" void kernel_launch(void* const* d_in, const int* in_sizes, int n_in,
                              void* d_out, int out_size, void* d_ws, size_t ws_size,
                              hipStream_t stream) {
  const float* acts       = (const float*)d_in[0];
  const int*   labels     = (const int*)d_in[1];
  const int*   act_lens   = (const int*)d_in[2];
  const int*   label_lens = (const int*)d_in[3];
  float* out = (float*)d_out;
  ushort* P   = (ushort*)d_ws;                       // B*TP*512B = 34.6 MB
  float*  Pbk = (float*)(P + (size_t)B * TP * RW);   // B*TP*8B   = 0.54 MB

  (void)hipMemsetAsync(out, 0, sizeof(float) * out_size, stream);
  ctc_probs_kernel<<<dim3(TP / 32, B), 256, 0, stream>>>(acts, labels, P, Pbk);
  ctc_dp_kernel<<<B, 64, 0, stream>>>(P, Pbk, labels, act_lens, label_lens, out);
}

// Round 12
// 142.875 us; speedup vs baseline: 1.0512x; 1.0512x over previous
//
#include <hip/hip_runtime.h>
#include <hip/hip_fp16.h>
#include <math.h>

// CTC forward loss (warp-ctc semantics). T=1024, B=64, V=128, L=256, S=513.
//
// Round 13: cooperative 8-wave DP per batch (2 waves/SIMD on 64 CUs).
//  Evidence R2..R11: single-wave DP pinned at ~150 cyc/step (busy ~80,
//  stall ~70) under every memory/instruction arrangement -> must raise
//  waves/SIMD. R5 failed by concentrating 8 full-batch streams on 8 CUs
//  (L1 limit). Here the S=513 cells are SPLIT across 8 waves of one block:
//  wave w owns core cells [64w, 64w+64) + left overlap [64w-64, 64w)
//  (redundant). Influence propagates <=2 cells/step, so the core stays
//  exact for 32 steps; overlap refreshed from the left neighbor's core via
//  LDS every 16 steps at ONE barrier (double-buffered slots). Renorm uses
//  a block-shared pow-2 scale (wave maxes -> LDS at step 13, combined
//  post-barrier). Cells left of 0 provably stay 0 (start 0, DPP injects 0)
//  so wave 0 needs no masking. Per wave per step: ~9 VALU + one 2B/lane
//  load (128 B/wave) -> ~1 KB/step/CU, 4x under R5's failure point.

#define L2E 1.4426950408889634f
#define LN2 0.6931471805599453f

constexpr int T   = 1024;
constexpr int B   = 64;
constexpr int V   = 128;
constexpr int L   = 256;
constexpr int RW  = 256;        // ushorts per P row: 256 label probs = 512 B
constexpr int TP  = T + 32;     // padded time rows per batch

typedef float v2f __attribute__((ext_vector_type(2)));

// ---- DPP helpers (gfx9 ctrl codes: 0x111+ row_shr, 0x138 wave_shr:1,
//      0x142 row_bcast15, 0x143 row_bcast31) ----
template <int CTRL>
__device__ __forceinline__ float fdpp0(float x) {        // invalid lanes -> 0
  return __int_as_float(__builtin_amdgcn_update_dpp(
      0, __float_as_int(x), CTRL, 0xf, 0xf, true));
}
template <int CTRL>
__device__ __forceinline__ float fdppk(float x) {        // invalid lanes -> keep
  return __int_as_float(__builtin_amdgcn_update_dpp(
      __float_as_int(x), __float_as_int(x), CTRL, 0xf, 0xf, false));
}

__device__ __forceinline__ float wave_bcast63(float x) {
  return __int_as_float(__builtin_amdgcn_readlane(__float_as_int(x), 63));
}

__device__ __forceinline__ float wave_max(float x) {     // any sign
  x = fmaxf(x, fdppk<0x111>(x));
  x = fmaxf(x, fdppk<0x112>(x));
  x = fmaxf(x, fdppk<0x114>(x));
  x = fmaxf(x, fdppk<0x118>(x));
  x = fmaxf(x, fdppk<0x142>(x));
  x = fmaxf(x, fdppk<0x143>(x));
  return wave_bcast63(x);
}
__device__ __forceinline__ float wave_sum_nn(float x) {  // x >= 0
  x += fdpp0<0x111>(x);
  x += fdpp0<0x112>(x);
  x += fdpp0<0x114>(x);
  x += fdpp0<0x118>(x);
  x += fdpp0<0x142>(x);
  x += fdpp0<0x143>(x);
  return wave_bcast63(x);
}

__device__ __forceinline__ float h2f(uint bits) {
  return __half2float(__ushort_as_half((ushort)bits));
}

// ---------------- prologue: emission probabilities ----------------
// One block per (b, 32-row chunk); 4 waves x 8 rows. Labels loaded once per
// wave. Output PLAIN-ORDER: P row ushort j = prob(lab[j]); blank stored as
// ONE fp32 per (b, t) in Pbk. Block x==32 (rows 1024..1055) is zero pad.
__global__ __launch_bounds__(256) void ctc_probs_kernel(
    const float* __restrict__ acts,        // (T, B, V)
    const int* __restrict__ labels,        // (B, L)
    ushort* __restrict__ P,                // (B, TP, RW) fp16 bits, 512B rows
    float* __restrict__ Pbk) {             // (B, TP) scalar blank probs
  const int w    = threadIdx.x >> 6;
  const int lane = threadIdx.x & 63;
  const int b    = blockIdx.y;
  const int tb   = blockIdx.x * 32 + w * 8;   // first of this wave's 8 rows

  if (tb >= T) {                            // pad rows: zeros
    #pragma unroll
    for (int r = 0; r < 8; ++r) {
      uint2 z; z.x = 0u; z.y = 0u;
      *(uint2*)(P + ((size_t)b * TP + tb + r) * RW + 4 * lane) = z;
    }
    if (lane < 8) Pbk[(size_t)b * TP + tb + lane] = 0.f;
    return;
  }

  // labels once per wave; bpermute addresses/shifts precomputed
  const int4 lvv = *(const int4*)(labels + (size_t)b * L + 4 * lane);
  const int ba0 = (lvv.x & ~1) * 2, sh0 = (lvv.x & 1) << 4;
  const int ba1 = (lvv.y & ~1) * 2, sh1 = (lvv.y & 1) << 4;
  const int ba2 = (lvv.z & ~1) * 2, sh2 = (lvv.z & 1) << 4;
  const int ba3 = (lvv.w & ~1) * 2, sh3 = (lvv.w & 1) << 4;

  #pragma unroll
  for (int r = 0; r < 8; ++r) {
    const int t = tb + r;
    const float* row = acts + ((size_t)t * B + b) * V;
    const float2 v2 = *(const float2*)(row + 2 * lane);
    const float e0 = exp2f(fmaf(v2.x, L2E, -32.0f));
    const float e1 = exp2f(fmaf(v2.y, L2E, -32.0f));
    const float sm = wave_sum_nn(e0 + e1);
    const float rc = __builtin_amdgcn_rcpf(sm);
    const auto pk = __builtin_amdgcn_cvt_pkrtz(e0 * rc, e1 * rc);
    uint hp;                                // [p_{2l} | p_{2l+1} << 16]
    __builtin_memcpy(&hp, &pk, 4);
    const uint g0 = (uint)__builtin_amdgcn_ds_bpermute(ba0, (int)hp);
    const uint g1 = (uint)__builtin_amdgcn_ds_bpermute(ba1, (int)hp);
    const uint g2 = (uint)__builtin_amdgcn_ds_bpermute(ba2, (int)hp);
    const uint g3 = (uint)__builtin_amdgcn_ds_bpermute(ba3, (int)hp);
    const uint h0 = (g0 >> sh0) & 0xffffu;
    const uint h1 = (g1 >> sh1) & 0xffffu;
    const uint h2 = (g2 >> sh2) & 0xffffu;
    const uint h3 = (g3 >> sh3);
    uint2 o;
    o.x = h0 | (h1 << 16);                  // PLAIN order: labels 4l,4l+1
    o.y = h2 | (h3 << 16);                  //              labels 4l+2,4l+3
    *(uint2*)(P + ((size_t)b * TP + t) * RW + 4 * lane) = o;
    if (lane == 0)
      Pbk[(size_t)b * TP + t] = e0 * rc;    // vocab 0 = lane0's p0
  }
}

// ---------------- DP kernel: 8 cooperating waves per batch ----------------
// Wave w, lane l holds pair index k = 32w-32+l -> cells (2k, 2k+1):
// even cell = blank-emission, odd cell = label k. Core = lanes 32..63
// (cells [64w, 64w+64)); lanes 0..31 = left overlap (refreshed every 16
// steps from wave w-1's core). Wave 7 lane 63 also owns cell 512 in a8.
__global__ __launch_bounds__(512) void ctc_dp_kernel(
    const ushort* __restrict__ P,
    const float* __restrict__ Pbk,
    const int* __restrict__ labels,
    const int* __restrict__ act_lens,
    const int* __restrict__ label_lens,
    float* __restrict__ out) {
  __shared__ float shc[2][9 * 64];   // [buf][slot*64+j]; slot w+1 = wave w core
  __shared__ float shm[2][8];        // per-wave maxes
  __shared__ float shs[8];           // epilogue partials
  const int b    = blockIdx.x;
  const int w    = threadIdx.x >> 6;
  const int lane = threadIdx.x & 63;
  const int k    = 32 * w - 32 + lane;     // global pair index (<0 on wave 0)
  const int kc   = (k < 0) ? 0 : k;
  const ushort* __restrict__ Pb = P + (size_t)b * TP * RW;
  const float*  __restrict__ Bk = Pbk + (size_t)b * TP;

  if (threadIdx.x < 64) {                  // slot 0 = zeros (wave 0's source)
    shc[0][threadIdx.x] = 0.f;
    shc[1][threadIdx.x] = 0.f;
  }

  // skip flag for odd cell 2k+1 (label k): needs lab[k] != lab[k-1], k>=1
  float f = 0.f;
  if (k >= 1) {
    const int la  = labels[(size_t)b * L + k];
    const int lam = labels[(size_t)b * L + k - 1];
    f = (la != 0 && la != lam) ? 1.f : 0.f;
  }

  const int AL = act_lens[b];
  const ushort* __restrict__ PbL = Pb + kc;  // lane's label-prob column

  // ---- t=0 init: cell0 = blank(0), cell1 = p(lab0, 0); rest 0 ----
  v2f Pp; Pp.x = 0.f; Pp.y = 0.f;
  float a8 = 0.f;
  {
    const float eb0 = Bk[0];
    const float e00 = h2f(PbL[0]);
    if (k == 0) { Pp.x = eb0; Pp.y = e00; }  // both waves holding k==0
  }
  int iacc = 0;

  // ---- prefetch: emissions 16 rows deep; blanks per block ----
  uint ev[16];
  #pragma unroll
  for (int j = 0; j < 16; ++j) ev[j] = PbL[(size_t)(1 + j) * RW];
  float bkq[16];
  #pragma unroll
  for (int j = 0; j < 16; ++j) bkq[j] = Bk[1 + j];

  const ushort* pf = PbL + (size_t)17 * RW;
  int t0 = 1;
  #pragma unroll 1
  for (int blk = 0; blk < 64; ++blk) {      // 64 x 16 = steps t=1..1024
    const int bb = blk & 1;
    float bkn[16];
    {
      const float* bn = Bk + (t0 + 16);     // rows <= 1039 < TP, pad zeroed
      #pragma unroll
      for (int j = 0; j < 16; ++j) bkn[j] = bn[j];
    }
    const ushort* pfA = pf;                 // dual bases: offsets fit 13-bit
    const ushort* pfB = pf + (size_t)8 * RW;
    const bool fast = (t0 + 16 <= AL);
    if (fast) {
      #pragma unroll
      for (int kk = 0; kk < 16; ++kk) {
        const uint uu = ev[kk];
        ev[kk] = ((kk < 8) ? pfA : pfB)[(size_t)(kk & 7) * RW];
        const float pc = fdpp0<0x138>(Pp.y);   // prev lane's odd cell
        const float e  = h2f(uu);
        const float sx = Pp.x + pc;
        const float ty = fmaf(f, pc, Pp.y + Pp.x);
        const float s8 = a8 + Pp.y;
        Pp.x = sx * bkq[kk];
        Pp.y = ty * e;
        a8 = s8 * bkq[kk];
        if (kk == 13) {                     // measure early: hide wave_max
          const float m = fmaxf(fmaxf(Pp.x, Pp.y), a8);
          const float pm = wave_max(m);
          if (lane == 0) shm[bb][w] = pm;
        }
      }
    } else {
      #pragma unroll
      for (int kk = 0; kk < 16; ++kk) {
        const uint uu = ev[kk];
        ev[kk] = ((kk < 8) ? pfA : pfB)[(size_t)(kk & 7) * RW];
        if ((t0 + kk) < AL) {               // AL block-uniform
          const float pc = fdpp0<0x138>(Pp.y);
          const float e  = h2f(uu);
          const float sx = Pp.x + pc;
          const float ty = fmaf(f, pc, Pp.y + Pp.x);
          const float s8 = a8 + Pp.y;
          Pp.x = sx * bkq[kk];
          Pp.y = ty * e;
          a8 = s8 * bkq[kk];
        }
        if (kk == 13) {
          const float m = fmaxf(fmaxf(Pp.x, Pp.y), a8);
          const float pm = wave_max(m);
          if (lane == 0) shm[bb][w] = pm;
        }
      }
    }
    // ---- boundary: core export, ONE barrier, refresh + shared scale ----
    if (lane >= 32)
      *(v2f*)&shc[bb][(w + 1) * 64 + 2 * (lane - 32)] = Pp;
    __syncthreads();
    const float* mm = shm[bb];
    const float bm = fmaxf(fmaxf(fmaxf(mm[0], mm[1]), fmaxf(mm[2], mm[3])),
                           fmaxf(fmaxf(mm[4], mm[5]), fmaxf(mm[6], mm[7])));
    if (lane < 32)
      Pp = *(const v2f*)&shc[bb][w * 64 + 2 * lane];
    {
      // pow-2 scale 2^(175-e), +48 headroom (validated R10/R11, absmax 0)
      const uint mb2 = __float_as_uint(bm);
      int e = (int)((mb2 >> 23) & 0xffu); if (e < 48) e = 48;
      const float r = __uint_as_float((uint)(302 - e) << 23);
      iacc += (e - 175);
      Pp.x *= r; Pp.y *= r; a8 *= r;
    }
    #pragma unroll
    for (int j = 0; j < 16; ++j) bkq[j] = bkn[j];
    t0 += 16;
    pf += (size_t)16 * RW;
  }

  // ---- epilogue: -ln( (a[end] + a[end-1]) * 2^iacc ) ----
  // contributions from CORE cells only (no double count with overlaps)
  const int end = 2 * label_lens[b];
  float sel = 0.f;
  if (lane >= 32) {
    const int c0 = 64 * w + 2 * (lane - 32);
    if (c0 == end || c0 == end - 1) sel += Pp.x;
    if (c0 + 1 == end || c0 + 1 == end - 1) sel += Pp.y;
  }
  if (w == 7 && lane == 63 && end == 512) sel += a8;
  sel = wave_sum_nn(sel);
  if (lane == 0) shs[w] = sel;
  __syncthreads();
  if (threadIdx.x == 0) {
    float s = 0.f;
    #pragma unroll
    for (int j = 0; j < 8; ++j) s += shs[j];
    const float cost = -((log2f(s) + (float)iacc) * LN2);
    atomicAdd(out, cost);
  }
}

extern "C" void kernel_launch(void* const* d_in, const int* in_sizes, int n_in,
                              void* d_out, int out_size, void* d_ws, size_t ws_size,
                              hipStream_t stream) {
  const float* acts       = (const float*)d_in[0];
  const int*   labels     = (const int*)d_in[1];
  const int*   act_lens   = (const int*)d_in[2];
  const int*   label_lens = (const int*)d_in[3];
  float* out = (float*)d_out;
  ushort* P   = (ushort*)d_ws;                       // B*TP*512B = 34.6 MB
  float*  Pbk = (float*)(P + (size_t)B * TP * RW);   // B*TP*4B   = 0.27 MB

  (void)hipMemsetAsync(out, 0, sizeof(float) * out_size, stream);
  ctc_probs_kernel<<<dim3(TP / 32, B), 256, 0, stream>>>(acts, labels, P, Pbk);
  ctc_dp_kernel<<<B, 512, 0, stream>>>(P, Pbk, labels, act_lens, label_lens, out);
}